// Round 9
// baseline (142.877 us; speedup 1.0000x reference)
//
#include <hip/hip_runtime.h>
#include <cstdint>
#include <cstddef>

// (B_, S, I, H) = (16, 2048, 256, 512)
#define BB 16
#define SS 2048
#define II 256
#define HH 512
#define MM (BB * SS)        /* 32768 GEMM rows              */
#define NNC 1024            /* GEMM cols = 2H re/im interlv */
#define SCHUNK 64           /* scan chunk (r4-verified)     */
#define SNCHUNK 32          /* chunks per batch             */

using bf16x8 = __attribute__((ext_vector_type(8))) short;
using short8 = __attribute__((ext_vector_type(8))) short;
using f32x4  = __attribute__((ext_vector_type(4))) float;

typedef __attribute__((address_space(3))) uint32_t       lds_u32;
typedef __attribute__((address_space(1))) const uint32_t glb_u32;

__device__ __forceinline__ short f2bf(float f) {
    uint32_t u = __float_as_uint(f);
    u += 0x7fffu + ((u >> 16) & 1u);   // RTNE
    return (short)(u >> 16);
}
__device__ __forceinline__ uint32_t packf16(float a, float b) {
    union { _Float16 h[2]; uint32_t u; } cv;
    cv.h[0] = (_Float16)a; cv.h[1] = (_Float16)b;
    return cv.u;
}
__device__ __forceinline__ float2 unpackf16(uint32_t u) {
    union { uint32_t u; _Float16 h[2]; } cv; cv.u = u;
    return make_float2((float)cv.h[0], (float)cv.h[1]);
}

// ---- fused converts (r4-verified bodies) ----
__global__ __launch_bounds__(256) void cvt_xb(const float4* __restrict__ x,
                                              short8* __restrict__ xb,
                                              const float* __restrict__ Bre,
                                              const float* __restrict__ Bim,
                                              short* __restrict__ Bc) {
    const int bid = blockIdx.x;
    if (bid < 4096) {
        int i = bid * 256 + threadIdx.x;
        float4 v0 = x[2 * i], v1 = x[2 * i + 1];
        short8 o;
        o[0]=f2bf(v0.x); o[1]=f2bf(v0.y); o[2]=f2bf(v0.z); o[3]=f2bf(v0.w);
        o[4]=f2bf(v1.x); o[5]=f2bf(v1.y); o[6]=f2bf(v1.z); o[7]=f2bf(v1.w);
        xb[i] = o;
    } else {
        int idx = (bid - 4096) * 256 + threadIdx.x;  // 32768
        int row = idx >> 5;                           // 0..1023
        int k0  = (idx & 31) << 3;                    // 0..248
        const float* src = ((row & 1) ? Bim : Bre) + (size_t)(row >> 1) * II + k0;
        float4 v0 = *(const float4*)src;
        float4 v1 = *(const float4*)(src + 4);
        short8 o;
        o[0]=f2bf(v0.x); o[1]=f2bf(v0.y); o[2]=f2bf(v0.z); o[3]=f2bf(v0.w);
        o[4]=f2bf(v1.x); o[5]=f2bf(v1.y); o[6]=f2bf(v1.z); o[7]=f2bf(v1.w);
        *(short8*)(Bc + (size_t)row * II + k0) = o;
    }
}

// ---- K1: XCD-swizzled GEMM + r4-verbatim Y write + one-pass serial E ----
union SMem {
    struct { short Al[2][128 * 32]; short Bl[2][128 * 32]; } g;  // 32 KiB GEMM stage
    uint32_t t2f[128 * 65];                                      // 33.3 KiB transpose
};

__global__ __launch_bounds__(256, 4) void gemm_scanE(const short* __restrict__ Xb,
                                                     const short* __restrict__ Bc,
                                                     const float* __restrict__ nu,
                                                     const float* __restrict__ th,
                                                     uint32_t* __restrict__ Y,
                                                     float2* __restrict__ E) {
    __shared__ SMem sm;

    // XCD-aware swizzle: 8 consecutive per-XCD blocks share one M-slab.
    const int xcd = blockIdx.x & 7;
    const int k   = blockIdx.x >> 3;          // 0..255
    const int mt  = xcd * 32 + (k >> 3);      // 0..255 (bijective)
    const int nt  = k & 7;
    const int m0 = mt * 128, n0 = nt * 128;
    const int t  = threadIdx.x;
    const int w  = t >> 6, l = t & 63;
    const int fr = l & 15, fg = l >> 4;
    const int wr = w >> 1, wc = w & 1;

    f32x4 acc[4][4] = {};

    // ---------------- main loop: r4-verbatim ----------------
#pragma unroll
    for (int i = 0; i < 2; ++i) {
        const int ch = i * 256 + t;
        __builtin_amdgcn_global_load_lds(
            (glb_u32*)(Xb + (size_t)(m0 + (ch >> 2)) * II + ((ch & 3) << 3)),
            (lds_u32*)&sm.g.Al[0][ch * 8], 16, 0, 0);
        __builtin_amdgcn_global_load_lds(
            (glb_u32*)(Bc + (size_t)(n0 + (ch >> 2)) * II + ((ch & 3) << 3)),
            (lds_u32*)&sm.g.Bl[0][ch * 8], 16, 0, 0);
    }
    __syncthreads();

    for (int ks = 0; ks < 8; ++ks) {
        const int cur = ks & 1, nxt = cur ^ 1;
        if (ks < 7) {
#pragma unroll
            for (int i = 0; i < 2; ++i) {
                const int ch = i * 256 + t;
                __builtin_amdgcn_global_load_lds(
                    (glb_u32*)(Xb + (size_t)(m0 + (ch >> 2)) * II + (ks + 1) * 32 + ((ch & 3) << 3)),
                    (lds_u32*)&sm.g.Al[nxt][ch * 8], 16, 0, 0);
                __builtin_amdgcn_global_load_lds(
                    (glb_u32*)(Bc + (size_t)(n0 + (ch >> 2)) * II + (ks + 1) * 32 + ((ch & 3) << 3)),
                    (lds_u32*)&sm.g.Bl[nxt][ch * 8], 16, 0, 0);
            }
        }
        bf16x8 a[4], b[4];
#pragma unroll
        for (int mi = 0; mi < 4; ++mi)
            a[mi] = *(const bf16x8*)&sm.g.Al[cur][(wr * 64 + mi * 16 + fr) * 32 + fg * 8];
#pragma unroll
        for (int ni = 0; ni < 4; ++ni)
            b[ni] = *(const bf16x8*)&sm.g.Bl[cur][(wc * 64 + ni * 16 + fr) * 32 + fg * 8];
#pragma unroll
        for (int mi = 0; mi < 4; ++mi)
#pragma unroll
            for (int ni = 0; ni < 4; ++ni)
                acc[mi][ni] = __builtin_amdgcn_mfma_f32_16x16x32_bf16(
                    a[mi], b[ni], acc[mi][ni], 0, 0, 0);
        __syncthreads();
    }

    // ---------------- Y write: r4 VERBATIM (verified) ----------------
#pragma unroll
    for (int mi = 0; mi < 4; ++mi)
#pragma unroll
        for (int ni = 0; ni < 4; ++ni) {
            const int row0 = m0 + wr * 64 + mi * 16 + fg * 4;
            const int ncol = n0 + wc * 64 + ni * 16 + fr;
#pragma unroll
            for (int r = 0; r < 4; ++r) {
                float v = acc[mi][ni][r];
                float o = __shfl_xor(v, 1);
                if (!(fr & 1))
                    Y[(size_t)(row0 + r) * HH + (ncol >> 1)] = packf16(v, o);
            }
        }

    // ------------- full-width transpose (aliases dead Al/Bl) -------------
    // All waves write all their tiles: col = wc*32 + ni*8 + fr/2 (0..63),
    // row = wr*64 + mi*16 + fg*4 + r (0..127). Bank-conflict-free (stride 65).
#pragma unroll
    for (int ni = 0; ni < 4; ++ni)
#pragma unroll
        for (int mi = 0; mi < 4; ++mi)
#pragma unroll
            for (int r = 0; r < 4; ++r) {
                const float v = acc[mi][ni][r];
                const float o = __shfl_xor(v, 1);
                if (!(fr & 1))
                    sm.t2f[(wr * 64 + mi * 16 + fg * 4 + r) * 65 +
                           (wc * 32 + ni * 8 + (fr >> 1))] = packf16(v, o);
            }
    __syncthreads();                               // T2f ready

    // ------------- one-pass serial E: 128 threads, r8-verbatim body -------------
    const int b_  = m0 >> 11;
    const int c64 = (m0 >> 6) & 31;
    if (t < 128) {
        const int chn = t & 63;
        const int hc  = t >> 6;
        const int gch = (n0 >> 1) + chn;
        const float env = __expf(nu[gch]);
        const float rad = __expf(-env);
        float s1, c1; __sincosf(th[gch], &s1, &c1);
        const float lre = rad * c1, lim = rad * s1;
        float hre = 0.f, him = 0.f;
        for (int i0 = 0; i0 < 64; i0 += 8) {
            uint32_t vv[8];
#pragma unroll
            for (int i = 0; i < 8; ++i)
                vv[i] = sm.t2f[(hc * 64 + i0 + i) * 65 + chn];
#pragma unroll
            for (int i = 0; i < 8; ++i) {
                const float2 v = unpackf16(vv[i]);
                const float nr = lre * hre - lim * him + v.x;
                him = lre * him + lim * hre + v.y;
                hre = nr;
            }
        }
        E[((size_t)b_ * SNCHUNK + c64 + hc) * HH + gch] = make_float2(hre, him);
    }
}

// ---- K2: serial carry across 32 chunks (r4 VERBATIM) ----
__global__ __launch_bounds__(512) void carry(const float2* __restrict__ E,
                                             const float* __restrict__ nu,
                                             const float* __restrict__ th,
                                             float2* __restrict__ P) {
    const int b = blockIdx.x;                 // 16
    const int h = threadIdx.x;                // 512
    const float env = __expf(nu[h]);
    const float rL  = __expf(-(float)SCHUNK * env);
    float s, cs; __sincosf((float)SCHUNK * th[h], &s, &cs);
    const float lre = rL * cs, lim = rL * s;
    float pre = 0.f, pim = 0.f;
#pragma unroll 4
    for (int c = 0; c < SNCHUNK; ++c) {
        const size_t idx = ((size_t)b * SNCHUNK + c) * HH + h;
        P[idx] = make_float2(pre, pim);
        const float2 e = E[idx];
        const float nr = lre * pre - lim * pim + e.x;
        pim = lre * pim + lim * pre + e.y;
        pre = nr;
    }
}

// ---- K3: final scan seeded with P over raw-Bx Y (r4 VERBATIM) ----
__global__ __launch_bounds__(512) void scan_final(const uint32_t* __restrict__ Y,
                                                  const float2* __restrict__ P,
                                                  const float* __restrict__ nu,
                                                  const float* __restrict__ th,
                                                  float* __restrict__ out) {
    const int g = blockIdx.x;                 // 512 = 16 b * 32 c
    const int b = g >> 5, c = g & 31;
    const int h = threadIdx.x;
    const float env = __expf(nu[h]);
    const float rad = __expf(-env);
    float s, cs; __sincosf(th[h], &s, &cs);
    const float lre = rad * cs, lim = rad * s;
    const float2 p = P[(size_t)g * HH + h];
    float hre = p.x, him = p.y;
    const uint32_t* yb = Y + ((size_t)b * SS + (size_t)c * SCHUNK) * HH + h;
    float* ob = out + ((size_t)b * SS + (size_t)c * SCHUNK) * NNC;
#pragma unroll 4
    for (int t = 0; t < SCHUNK; ++t) {
        float2 y = unpackf16(yb[(size_t)t * HH]);
        const float nr = lre * hre - lim * him + y.x;
        him = lre * him + lim * hre + y.y;
        hre = nr;
        ob[(size_t)t * NNC + h]      = hre;
        ob[(size_t)t * NNC + HH + h] = him;
    }
}

extern "C" void kernel_launch(void* const* d_in, const int* in_sizes, int n_in,
                              void* d_out, int out_size, void* d_ws, size_t ws_size,
                              hipStream_t stream) {
    const float* x   = (const float*)d_in[0];
    const float* nu  = (const float*)d_in[1];
    const float* th  = (const float*)d_in[2];
    const float* Bre = (const float*)d_in[3];
    const float* Bim = (const float*)d_in[4];
    float* out = (float*)d_out;

    // ws: Xb bf16 16 MiB | Bc bf16 512 KiB | Y u32 64 MiB | E 2 MiB | P 2 MiB
    char* ws = (char*)d_ws;
    short*    Xb = (short*)ws;
    short*    Bc = (short*)(ws + (size_t)MM * II * 2);
    uint32_t* Y  = (uint32_t*)(ws + (size_t)MM * II * 2 + (size_t)NNC * II * 2);
    float2*   E  = (float2*)((char*)Y + (size_t)MM * HH * 4);
    float2*   P  = E + (size_t)BB * SNCHUNK * HH;

    cvt_xb<<<4096 + 128, 256, 0, stream>>>((const float4*)x, (short8*)Xb, Bre, Bim, Bc);
    gemm_scanE<<<(MM / 128) * (NNC / 128), 256, 0, stream>>>(Xb, Bc, nu, th, Y, E);
    carry<<<BB, HH, 0, stream>>>(E, nu, th, P);
    scan_final<<<BB * SNCHUNK, HH, 0, stream>>>(Y, P, nu, th, out);
}

// Round 10
// 92.363 us; speedup vs baseline: 1.5469x; 1.5469x over previous
//
#include <hip/hip_runtime.h>
#include <cstdint>
#include <cstddef>

// (B_, S, I, H) = (16, 2048, 256, 512)
#define BB 16
#define SS 2048
#define II 256
#define HH 512
#define MM (BB * SS)        /* 32768 GEMM rows        */
#define NNC 1024            /* out row width (re|im)  */
#define CHUNK 64
#define NCHUNK (SS / CHUNK) /* 32 chunks per batch    */

using bf16x8 = __attribute__((ext_vector_type(8))) short;
using short8 = __attribute__((ext_vector_type(8))) short;
using f32x4  = __attribute__((ext_vector_type(4))) float;

typedef __attribute__((address_space(3))) uint32_t       lds_u32;
typedef __attribute__((address_space(1))) const uint32_t glb_u32;

__device__ __forceinline__ short f2bf(float f) {
    uint32_t u = __float_as_uint(f);
    u += 0x7fffu + ((u >> 16) & 1u);   // RTNE
    return (short)(u >> 16);
}
__device__ __forceinline__ uint32_t packf16(float a, float b) {
    union { _Float16 h[2]; uint32_t u; } cv;
    cv.h[0] = (_Float16)a; cv.h[1] = (_Float16)b;
    return cv.u;
}
__device__ __forceinline__ float2 unpackf16(uint32_t u) {
    union { uint32_t u; _Float16 h[2]; } cv; cv.u = u;
    return make_float2((float)cv.h[0], (float)cv.h[1]);
}

// ---- fused converts (r4-verified bodies) ----
__global__ __launch_bounds__(256) void cvt_xb(const float4* __restrict__ x,
                                              short8* __restrict__ xb,
                                              const float* __restrict__ Bre,
                                              const float* __restrict__ Bim,
                                              short* __restrict__ Bc) {
    const int bid = blockIdx.x;
    if (bid < 4096) {
        int i = bid * 256 + threadIdx.x;
        float4 v0 = x[2 * i], v1 = x[2 * i + 1];
        short8 o;
        o[0]=f2bf(v0.x); o[1]=f2bf(v0.y); o[2]=f2bf(v0.z); o[3]=f2bf(v0.w);
        o[4]=f2bf(v1.x); o[5]=f2bf(v1.y); o[6]=f2bf(v1.z); o[7]=f2bf(v1.w);
        xb[i] = o;
    } else {
        int idx = (bid - 4096) * 256 + threadIdx.x;  // 32768
        int row = idx >> 5;                           // 0..1023
        int k0  = (idx & 31) << 3;                    // 0..248
        const float* src = ((row & 1) ? Bim : Bre) + (size_t)(row >> 1) * II + k0;
        float4 v0 = *(const float4*)src;
        float4 v1 = *(const float4*)(src + 4);
        short8 o;
        o[0]=f2bf(v0.x); o[1]=f2bf(v0.y); o[2]=f2bf(v0.z); o[3]=f2bf(v0.w);
        o[4]=f2bf(v1.x); o[5]=f2bf(v1.y); o[6]=f2bf(v1.z); o[7]=f2bf(v1.w);
        *(short8*)(Bc + (size_t)row * II + k0) = o;
    }
}

// ---- GEMM: r4 VERBATIM body (acc dies at Y-write) + XCD-aware swizzle ----
__global__ __launch_bounds__(256, 3) void gemm_pack(const short* __restrict__ Xb,
                                                    const short* __restrict__ Bc,
                                                    uint32_t* __restrict__ Y) {
    __shared__ short Al[2][128 * 32];
    __shared__ short Bl[2][128 * 32];

    // XCD-aware swizzle (r9-verified bijective): blocks sharing an M-slab
    // land on one XCD -> Xb panel read once per XCD L2, FETCH 70->27 MB.
    const int xcd = blockIdx.x & 7;
    const int k   = blockIdx.x >> 3;          // 0..255
    const int mt  = xcd * 32 + (k >> 3);      // 0..255
    const int nt  = k & 7;
    const int m0 = mt * 128, n0 = nt * 128;
    const int t  = threadIdx.x;
    const int w  = t >> 6, l = t & 63;
    const int fr = l & 15, fg = l >> 4;
    const int wr = w >> 1, wc = w & 1;

    f32x4 acc[4][4] = {};

    // prologue: stage k-step 0
#pragma unroll
    for (int i = 0; i < 2; ++i) {
        const int ch = i * 256 + t;
        __builtin_amdgcn_global_load_lds(
            (glb_u32*)(Xb + (size_t)(m0 + (ch >> 2)) * II + ((ch & 3) << 3)),
            (lds_u32*)&Al[0][ch * 8], 16, 0, 0);
        __builtin_amdgcn_global_load_lds(
            (glb_u32*)(Bc + (size_t)(n0 + (ch >> 2)) * II + ((ch & 3) << 3)),
            (lds_u32*)&Bl[0][ch * 8], 16, 0, 0);
    }
    __syncthreads();

    for (int ks = 0; ks < 8; ++ks) {         // K = 8 * 32
        const int cur = ks & 1, nxt = cur ^ 1;
        if (ks < 7) {
#pragma unroll
            for (int i = 0; i < 2; ++i) {
                const int ch = i * 256 + t;
                __builtin_amdgcn_global_load_lds(
                    (glb_u32*)(Xb + (size_t)(m0 + (ch >> 2)) * II + (ks + 1) * 32 + ((ch & 3) << 3)),
                    (lds_u32*)&Al[nxt][ch * 8], 16, 0, 0);
                __builtin_amdgcn_global_load_lds(
                    (glb_u32*)(Bc + (size_t)(n0 + (ch >> 2)) * II + (ks + 1) * 32 + ((ch & 3) << 3)),
                    (lds_u32*)&Bl[nxt][ch * 8], 16, 0, 0);
            }
        }
        bf16x8 a[4], b[4];
#pragma unroll
        for (int mi = 0; mi < 4; ++mi)
            a[mi] = *(const bf16x8*)&Al[cur][(wr * 64 + mi * 16 + fr) * 32 + fg * 8];
#pragma unroll
        for (int ni = 0; ni < 4; ++ni)
            b[ni] = *(const bf16x8*)&Bl[cur][(wc * 64 + ni * 16 + fr) * 32 + fg * 8];
#pragma unroll
        for (int mi = 0; mi < 4; ++mi)
#pragma unroll
            for (int ni = 0; ni < 4; ++ni)
                acc[mi][ni] = __builtin_amdgcn_mfma_f32_16x16x32_bf16(
                    a[mi], b[ni], acc[mi][ni], 0, 0, 0);
        __syncthreads();
    }

    // epilogue: r4 VERBATIM packed Y write (acc last use here)
#pragma unroll
    for (int mi = 0; mi < 4; ++mi)
#pragma unroll
        for (int ni = 0; ni < 4; ++ni) {
            const int row0 = m0 + wr * 64 + mi * 16 + fg * 4;
            const int ncol = n0 + wc * 64 + ni * 16 + fr;
#pragma unroll
            for (int r = 0; r < 4; ++r) {
                float v = acc[mi][ni][r];
                float o = __shfl_xor(v, 1);
                if (!(fr & 1))
                    Y[(size_t)(row0 + r) * HH + (ncol >> 1)] = packf16(v, o);
            }
        }
}

// ---- local chunk scan (h0=0) over packed Y -> chunk-end state E (r4 VERBATIM) ----
__global__ __launch_bounds__(512) void scan_e(const uint32_t* __restrict__ Y,
                                              const float* __restrict__ nu,
                                              const float* __restrict__ th,
                                              float2* __restrict__ E) {
    const int g = blockIdx.x;                 // 512 = 16 b * 32 c
    const int b = g >> 5, c = g & 31;
    const int h = threadIdx.x;
    const float env = __expf(nu[h]);
    const float rad = __expf(-env);
    float s, cs; __sincosf(th[h], &s, &cs);
    const float lre = rad * cs, lim = rad * s;
    const uint32_t* base = Y + ((size_t)b * SS + (size_t)c * CHUNK) * HH + h;
    float hre = 0.f, him = 0.f;
#pragma unroll 8
    for (int t = 0; t < CHUNK; ++t) {
        float2 y = unpackf16(base[(size_t)t * HH]);
        const float nr = lre * hre - lim * him + y.x;
        him = lre * him + lim * hre + y.y;
        hre = nr;
    }
    E[(size_t)g * HH + h] = make_float2(hre, him);
}

// ---- serial carry across chunks: P[c] = state entering chunk c (r4 VERBATIM) ----
__global__ __launch_bounds__(512) void carry(const float2* __restrict__ E,
                                             const float* __restrict__ nu,
                                             const float* __restrict__ th,
                                             float2* __restrict__ P) {
    const int b = blockIdx.x;                 // 16
    const int h = threadIdx.x;                // 512
    const float env = __expf(nu[h]);
    const float rL  = __expf(-(float)CHUNK * env);
    float s, cs; __sincosf((float)CHUNK * th[h], &s, &cs);
    const float lre = rL * cs, lim = rL * s;
    float pre = 0.f, pim = 0.f;
#pragma unroll 4
    for (int c = 0; c < NCHUNK; ++c) {
        const size_t idx = ((size_t)b * NCHUNK + c) * HH + h;
        P[idx] = make_float2(pre, pim);
        const float2 e = E[idx];
        const float nr = lre * pre - lim * pim + e.x;
        pim = lre * pim + lim * pre + e.y;
        pre = nr;
    }
}

// ---- final scan seeded with P; write out f32 re|im once (r4 VERBATIM) ----
__global__ __launch_bounds__(512) void scan_final(const uint32_t* __restrict__ Y,
                                                  const float2* __restrict__ P,
                                                  const float* __restrict__ nu,
                                                  const float* __restrict__ th,
                                                  float* __restrict__ out) {
    const int g = blockIdx.x;
    const int b = g >> 5, c = g & 31;
    const int h = threadIdx.x;
    const float env = __expf(nu[h]);
    const float rad = __expf(-env);
    float s, cs; __sincosf(th[h], &s, &cs);
    const float lre = rad * cs, lim = rad * s;
    const float2 p = P[(size_t)g * HH + h];
    float hre = p.x, him = p.y;
    const uint32_t* yb = Y + ((size_t)b * SS + (size_t)c * CHUNK) * HH + h;
    float* ob = out + ((size_t)b * SS + (size_t)c * CHUNK) * NNC;
#pragma unroll 4
    for (int t = 0; t < CHUNK; ++t) {
        float2 y = unpackf16(yb[(size_t)t * HH]);
        const float nr = lre * hre - lim * him + y.x;
        him = lre * him + lim * hre + y.y;
        hre = nr;
        ob[(size_t)t * NNC + h]      = hre;
        ob[(size_t)t * NNC + HH + h] = him;
    }
}

extern "C" void kernel_launch(void* const* d_in, const int* in_sizes, int n_in,
                              void* d_out, int out_size, void* d_ws, size_t ws_size,
                              hipStream_t stream) {
    const float* x   = (const float*)d_in[0];
    const float* nu  = (const float*)d_in[1];
    const float* th  = (const float*)d_in[2];
    const float* Bre = (const float*)d_in[3];
    const float* Bim = (const float*)d_in[4];
    float* out = (float*)d_out;

    // ws: Xb bf16 16 MiB | Bc bf16 512 KiB | Y u32 64 MiB | E 2 MiB | P 2 MiB
    char* ws = (char*)d_ws;
    short*    Xb = (short*)ws;
    short*    Bc = (short*)(ws + (size_t)MM * II * 2);
    uint32_t* Y  = (uint32_t*)(ws + (size_t)MM * II * 2 + (size_t)NNC * II * 2);
    float2*   E  = (float2*)((char*)Y + (size_t)MM * HH * 4);
    float2*   P  = E + (size_t)BB * NCHUNK * HH;

    cvt_xb<<<4096 + 128, 256, 0, stream>>>((const float4*)x, (short8*)Xb, Bre, Bim, Bc);
    gemm_pack<<<(MM / 128) * (NNC / 128), 256, 0, stream>>>(Xb, Bc, Y);
    scan_e<<<BB * NCHUNK, HH, 0, stream>>>(Y, nu, th, E);
    carry<<<BB, HH, 0, stream>>>(E, nu, th, P);
    scan_final<<<BB * NCHUNK, HH, 0, stream>>>(Y, P, nu, th, out);
}

// Round 12
// 90.505 us; speedup vs baseline: 1.5787x; 1.0205x over previous
//
#include <hip/hip_runtime.h>
#include <cstdint>
#include <cstddef>

// (B_, S, I, H) = (16, 2048, 256, 512)
#define BB 16
#define SS 2048
#define II 256
#define HH 512
#define MM (BB * SS)        /* 32768 GEMM rows        */
#define NNC 1024            /* out row width (re|im)  */
#define CHUNK 64
#define NCHUNK (SS / CHUNK) /* 32 chunks per batch    */

using bf16x8 = __attribute__((ext_vector_type(8))) short;
using short8 = __attribute__((ext_vector_type(8))) short;
using f32x4  = __attribute__((ext_vector_type(4))) float;

typedef __attribute__((address_space(3))) uint32_t       lds_u32;
typedef __attribute__((address_space(1))) const uint32_t glb_u32;

__device__ __forceinline__ short f2bf(float f) {
    uint32_t u = __float_as_uint(f);
    u += 0x7fffu + ((u >> 16) & 1u);   // RTNE
    return (short)(u >> 16);
}
__device__ __forceinline__ uint32_t packf16(float a, float b) {
    union { _Float16 h[2]; uint32_t u; } cv;
    cv.h[0] = (_Float16)a; cv.h[1] = (_Float16)b;
    return cv.u;
}
__device__ __forceinline__ float2 unpackf16(uint32_t u) {
    union { uint32_t u; _Float16 h[2]; } cv; cv.u = u;
    return make_float2((float)cv.h[0], (float)cv.h[1]);
}

// ---- fused converts (r4/r10-verified bodies) ----
__global__ __launch_bounds__(256) void cvt_xb(const float4* __restrict__ x,
                                              short8* __restrict__ xb,
                                              const float* __restrict__ Bre,
                                              const float* __restrict__ Bim,
                                              short* __restrict__ Bc) {
    const int bid = blockIdx.x;
    if (bid < 4096) {
        int i = bid * 256 + threadIdx.x;
        float4 v0 = x[2 * i], v1 = x[2 * i + 1];
        short8 o;
        o[0]=f2bf(v0.x); o[1]=f2bf(v0.y); o[2]=f2bf(v0.z); o[3]=f2bf(v0.w);
        o[4]=f2bf(v1.x); o[5]=f2bf(v1.y); o[6]=f2bf(v1.z); o[7]=f2bf(v1.w);
        xb[i] = o;
    } else {
        int idx = (bid - 4096) * 256 + threadIdx.x;  // 32768
        int row = idx >> 5;                           // 0..1023
        int k0  = (idx & 31) << 3;                    // 0..248
        const float* src = ((row & 1) ? Bim : Bre) + (size_t)(row >> 1) * II + k0;
        float4 v0 = *(const float4*)src;
        float4 v1 = *(const float4*)(src + 4);
        short8 o;
        o[0]=f2bf(v0.x); o[1]=f2bf(v0.y); o[2]=f2bf(v0.z); o[3]=f2bf(v0.w);
        o[4]=f2bf(v1.x); o[5]=f2bf(v1.y); o[6]=f2bf(v1.z); o[7]=f2bf(v1.w);
        *(short8*)(Bc + (size_t)row * II + k0) = o;
    }
}

// ---- GEMM: r10 VERBATIM (verified; XCD-swizzled, acc dies at Y-write) ----
__global__ __launch_bounds__(256, 3) void gemm_pack(const short* __restrict__ Xb,
                                                    const short* __restrict__ Bc,
                                                    uint32_t* __restrict__ Y) {
    __shared__ short Al[2][128 * 32];
    __shared__ short Bl[2][128 * 32];

    const int xcd = blockIdx.x & 7;
    const int k   = blockIdx.x >> 3;          // 0..255
    const int mt  = xcd * 32 + (k >> 3);      // 0..255
    const int nt  = k & 7;
    const int m0 = mt * 128, n0 = nt * 128;
    const int t  = threadIdx.x;
    const int w  = t >> 6, l = t & 63;
    const int fr = l & 15, fg = l >> 4;
    const int wr = w >> 1, wc = w & 1;

    f32x4 acc[4][4] = {};

#pragma unroll
    for (int i = 0; i < 2; ++i) {
        const int ch = i * 256 + t;
        __builtin_amdgcn_global_load_lds(
            (glb_u32*)(Xb + (size_t)(m0 + (ch >> 2)) * II + ((ch & 3) << 3)),
            (lds_u32*)&Al[0][ch * 8], 16, 0, 0);
        __builtin_amdgcn_global_load_lds(
            (glb_u32*)(Bc + (size_t)(n0 + (ch >> 2)) * II + ((ch & 3) << 3)),
            (lds_u32*)&Bl[0][ch * 8], 16, 0, 0);
    }
    __syncthreads();

    for (int ks = 0; ks < 8; ++ks) {         // K = 8 * 32
        const int cur = ks & 1, nxt = cur ^ 1;
        if (ks < 7) {
#pragma unroll
            for (int i = 0; i < 2; ++i) {
                const int ch = i * 256 + t;
                __builtin_amdgcn_global_load_lds(
                    (glb_u32*)(Xb + (size_t)(m0 + (ch >> 2)) * II + (ks + 1) * 32 + ((ch & 3) << 3)),
                    (lds_u32*)&Al[nxt][ch * 8], 16, 0, 0);
                __builtin_amdgcn_global_load_lds(
                    (glb_u32*)(Bc + (size_t)(n0 + (ch >> 2)) * II + (ks + 1) * 32 + ((ch & 3) << 3)),
                    (lds_u32*)&Bl[nxt][ch * 8], 16, 0, 0);
            }
        }
        bf16x8 a[4], b[4];
#pragma unroll
        for (int mi = 0; mi < 4; ++mi)
            a[mi] = *(const bf16x8*)&Al[cur][(wr * 64 + mi * 16 + fr) * 32 + fg * 8];
#pragma unroll
        for (int ni = 0; ni < 4; ++ni)
            b[ni] = *(const bf16x8*)&Bl[cur][(wc * 64 + ni * 16 + fr) * 32 + fg * 8];
#pragma unroll
        for (int mi = 0; mi < 4; ++mi)
#pragma unroll
            for (int ni = 0; ni < 4; ++ni)
                acc[mi][ni] = __builtin_amdgcn_mfma_f32_16x16x32_bf16(
                    a[mi], b[ni], acc[mi][ni], 0, 0, 0);
        __syncthreads();
    }

#pragma unroll
    for (int mi = 0; mi < 4; ++mi)
#pragma unroll
        for (int ni = 0; ni < 4; ++ni) {
            const int row0 = m0 + wr * 64 + mi * 16 + fg * 4;
            const int ncol = n0 + wc * 64 + ni * 16 + fr;
#pragma unroll
            for (int r = 0; r < 4; ++r) {
                float v = acc[mi][ni][r];
                float o = __shfl_xor(v, 1);
                if (!(fr & 1))
                    Y[(size_t)(row0 + r) * HH + (ncol >> 1)] = packf16(v, o);
            }
        }
}

// ---- local chunk scan (h0=0) over packed Y -> chunk-end state E (r10 VERBATIM) ----
__global__ __launch_bounds__(512) void scan_e(const uint32_t* __restrict__ Y,
                                              const float* __restrict__ nu,
                                              const float* __restrict__ th,
                                              float2* __restrict__ E) {
    const int g = blockIdx.x;                 // 512 = 16 b * 32 c
    const int b = g >> 5, c = g & 31;
    const int h = threadIdx.x;
    const float env = __expf(nu[h]);
    const float rad = __expf(-env);
    float s, cs; __sincosf(th[h], &s, &cs);
    const float lre = rad * cs, lim = rad * s;
    const uint32_t* base = Y + ((size_t)b * SS + (size_t)c * CHUNK) * HH + h;
    float hre = 0.f, him = 0.f;
#pragma unroll 8
    for (int t = 0; t < CHUNK; ++t) {
        float2 y = unpackf16(base[(size_t)t * HH]);
        const float nr = lre * hre - lim * him + y.x;
        him = lre * him + lim * hre + y.y;
        hre = nr;
    }
    E[(size_t)g * HH + h] = make_float2(hre, him);
}

// ---- final scan: inline carry from E (<=31 MACs, L2-hit) + r10 scan body ----
__global__ __launch_bounds__(512) void scan_final(const uint32_t* __restrict__ Y,
                                                  const float2* __restrict__ E,
                                                  const float* __restrict__ nu,
                                                  const float* __restrict__ th,
                                                  float* __restrict__ out) {
    const int g = blockIdx.x;                 // 512 = 16 b * 32 c
    const int b = g >> 5, c = g & 31;
    const int h = threadIdx.x;
    const float env = __expf(nu[h]);
    const float rad = __expf(-env);
    float s, cs; __sincosf(th[h], &s, &cs);
    const float lre = rad * cs, lim = rad * s;

    // inline carry: P = sum_{j<c} lam64^{c-1-j} * E[b,j]   (r10 recurrence order)
    const float rL = __expf(-(float)CHUNK * env);
    float sL, cL; __sincosf((float)CHUNK * th[h], &sL, &cL);
    const float l64re = rL * cL, l64im = rL * sL;
    float pre = 0.f, pim = 0.f;
    for (int j = 0; j < c; ++j) {
        const float2 e = E[((size_t)(b * NCHUNK + j)) * HH + h];
        const float nr = l64re * pre - l64im * pim + e.x;
        pim = l64re * pim + l64im * pre + e.y;
        pre = nr;
    }

    float hre = pre, him = pim;
    const uint32_t* yb = Y + ((size_t)b * SS + (size_t)c * CHUNK) * HH + h;
    float* ob = out + ((size_t)b * SS + (size_t)c * CHUNK) * NNC;
#pragma unroll 4
    for (int t = 0; t < CHUNK; ++t) {
        float2 y = unpackf16(yb[(size_t)t * HH]);
        const float nr = lre * hre - lim * him + y.x;
        him = lre * him + lim * hre + y.y;
        hre = nr;
        ob[(size_t)t * NNC + h]      = hre;
        ob[(size_t)t * NNC + HH + h] = him;
    }
}

extern "C" void kernel_launch(void* const* d_in, const int* in_sizes, int n_in,
                              void* d_out, int out_size, void* d_ws, size_t ws_size,
                              hipStream_t stream) {
    const float* x   = (const float*)d_in[0];
    const float* nu  = (const float*)d_in[1];
    const float* th  = (const float*)d_in[2];
    const float* Bre = (const float*)d_in[3];
    const float* Bim = (const float*)d_in[4];
    float* out = (float*)d_out;

    // ws: Xb bf16 16 MiB | Bc bf16 512 KiB | Y u32 64 MiB | E 2 MiB
    char* ws = (char*)d_ws;
    short*    Xb = (short*)ws;
    short*    Bc = (short*)(ws + (size_t)MM * II * 2);
    uint32_t* Y  = (uint32_t*)(ws + (size_t)MM * II * 2 + (size_t)NNC * II * 2);
    float2*   E  = (float2*)((char*)Y + (size_t)MM * HH * 4);

    cvt_xb<<<4096 + 128, 256, 0, stream>>>((const float4*)x, (short8*)Xb, Bre, Bim, Bc);
    gemm_pack<<<(MM / 128) * (NNC / 128), 256, 0, stream>>>(Xb, Bc, Y);
    scan_e<<<BB * NCHUNK, HH, 0, stream>>>(Y, nu, th, E);
    scan_final<<<BB * NCHUNK, HH, 0, stream>>>(Y, E, nu, th, out);
}